// Round 6
// baseline (1198.002 us; speedup 1.0000x reference)
//
#include <hip/hip_runtime.h>
#include <math.h>

#define NN 12288
#define DD 128
#define EPSF 1e-7f
#define MAXNORM (1.0f - 1e-3f)
#define CSPLIT 4
#define CCOLS (NN / CSPLIT)      /* 3072 columns per block */
#define CSTEPS (CCOLS / 128)     /* 24 steps of 128 columns */
#define SLABS (CSTEPS / 4)       /* 6 LDS slabs of 512 columns */

typedef __attribute__((ext_vector_type(8))) short short8_t;
typedef __attribute__((ext_vector_type(4))) float float4_t;
typedef unsigned short ushort_t;

__device__ __forceinline__ unsigned short f2bf(float f) {
    unsigned int u = __builtin_bit_cast(unsigned int, f);
    unsigned int r = u + 0x7FFFu + ((u >> 16) & 1u);
    return (unsigned short)(r >> 16);
}

// ---------------- Kernel 1: per-row prep ----------------
__global__ __launch_bounds__(128) void prep_kernel(
    const float* __restrict__ x, const float* __restrict__ a,
    ushort_t* __restrict__ xtb,
    float* __restrict__ wh1, float* __restrict__ wh2)
{
    const int r = blockIdx.x;
    const int t = threadIdx.x;
    const float xv = x[r * DD + t];
    const float a1 = a[t];
    const float a2 = a[DD + t];
    float s0 = xv * xv, s1 = xv * a1, s2 = xv * a2;
    #pragma unroll
    for (int o = 32; o > 0; o >>= 1) {
        s0 += __shfl_xor(s0, o);
        s1 += __shfl_xor(s1, o);
        s2 += __shfl_xor(s2, o);
    }
    __shared__ float red[6];
    const int w = t >> 6;
    if ((t & 63) == 0) { red[w * 3 + 0] = s0; red[w * 3 + 1] = s1; red[w * 3 + 2] = s2; }
    __syncthreads();
    const float sumsq = red[0] + red[3];
    const float d1    = red[1] + red[4];
    const float d2    = red[2] + red[5];
    const float nraw  = sqrtf(sumsq);
    const float nrm   = fminf(fmaxf(nraw, EPSF), 1.0f - EPSF);
    const float scale = atanhf(nrm) / nrm;
    xtb[(size_t)r * DD + t] = f2bf(xv * scale);
    if (t == 0) {
        wh1[r] = scale * d1;
        wh2[r] = scale * d2;
    }
}

// ---------------- Kernel 2: build xtB in MFMA-B-fragment-linear layout ----
// chunk C (32 j), dt: 1 KB block; element (lane, e) = xt[C*32+(lane>>4)*8+e][dt*16+(lane&15)]
__global__ __launch_bounds__(256) void swizzle_kernel(
    const ushort_t* __restrict__ xtb, ushort_t* __restrict__ xtB)
{
    __shared__ ushort_t raw[32 * 136];
    const int C = blockIdx.x;
    const int t = threadIdx.x;
    #pragma unroll
    for (int p = 0; p < 2; ++p) {
        const int idx = p * 256 + t;
        const int j = idx >> 4, cell = idx & 15;
        const uint4 v = *(const uint4*)(xtb + (size_t)(C * 32 + j) * DD + cell * 8);
        *(uint4*)&raw[j * 136 + cell * 8] = v;
    }
    __syncthreads();
    #pragma unroll
    for (int p = 0; p < 2; ++p) {
        const int oc = p * 256 + t;       // 0..511 = dt*64 + lane
        const int dt = oc >> 6;
        const int l6 = oc & 63;
        const int l15 = l6 & 15, q = l6 >> 4;
        short8_t v;
        #pragma unroll
        for (int e = 0; e < 8; ++e)
            v[e] = (short)raw[(q * 8 + e) * 136 + dt * 16 + l15];
        *(short8_t*)(xtB + (size_t)C * 4096 + oc * 8) = v;
    }
}

// ---------------- Kernel 3: flash MFMA attention, slab-sequential B ----------
// grid (192, 4), 1 block/CU (140 KB LDS), 768 blocks = exactly 3 rounds.
// Block = 64 rows x 3072 cols. The 3072 cols are 6 sequential 512-col LDS
// slabs (128 KB, staged once each: barrier -> ping-pong reg copy -> barrier,
// only 6 restages/block). Between restages the inner loop is round-0's
// verified structure: distance-2 adj prefetch through 3 rotating int4[8]
// buffers, conflict-free ds_read_b128 B, NO barriers. acc + lsum persist
// across all 24 steps -> CSPLIT=4 partials (50 MB round-trip vs r0's 302).
__global__ __launch_bounds__(256, 1) void attn_kernel(
    const int* __restrict__ adj,
    const ushort_t* __restrict__ xtB,
    const float* __restrict__ wh1, const float* __restrict__ wh2,
    float* __restrict__ pout, float* __restrict__ plsum)
{
    __shared__ __align__(16) ushort_t B_lds[512 * DD];   // 128 KB
    __shared__ __align__(16) float wh2_lds[CCOLS];       // 12 KB

    const int t = threadIdx.x;
    const int w = t >> 6, lane = t & 63;
    const int l15 = lane & 15, quad = lane >> 4;
    const int cy = blockIdx.y;
    const int jcol0 = cy * CCOLS;
    const int rowbase = blockIdx.x * 64 + w * 16;    // wave's 16 rows

    #pragma unroll
    for (int m = 0; m < CCOLS / 256; ++m)
        wh2_lds[m * 256 + t] = wh2[jcol0 + m * 256 + t];
    const float wh1i = wh1[rowbase + l15];

    const int* adj_lane = adj + (size_t)(rowbase + l15) * NN + jcol0 + quad * 8;
    // slab sl = 128 KB contiguous: Bsrc + sl*8192 uint4
    const uint4* Bsrc = (const uint4*)(xtB + (size_t)(jcol0 >> 5) * 4096);

    float4_t acc[8];
    #pragma unroll
    for (int dt = 0; dt < 8; ++dt) acc[dt] = (float4_t)0.0f;
    float lsum = 0.0f;

    int4 A0[8], A1[8], A2[8];     // adj rotating buffers (static indexing)

    auto adj_load = [&](int st, int4 (&A)[8]) {
        const int* bp = adj_lane + st * 128;
        #pragma unroll
        for (int kc = 0; kc < 4; ++kc) {
            A[kc * 2 + 0] = *(const int4*)(bp + kc * 32);
            A[kc * 2 + 1] = *(const int4*)(bp + kc * 32 + 4);
        }
    };

    // stage one 512-col slab (128 KB): 32 uint4/thread, ping-pong 8-batches
    auto stage = [&](int sl) {
        const uint4* sp = Bsrc + (size_t)sl * 8192 + t;
        uint4* d = (uint4*)B_lds + t;
        uint4 sa[8], sb[8];
        #pragma unroll
        for (int m = 0; m < 8; ++m) sa[m] = sp[m * 256];
        #pragma unroll
        for (int m = 0; m < 8; ++m) sb[m] = sp[(8 + m) * 256];
        #pragma unroll
        for (int m = 0; m < 8; ++m) d[m * 256] = sa[m];
        #pragma unroll
        for (int m = 0; m < 8; ++m) sa[m] = sp[(16 + m) * 256];
        #pragma unroll
        for (int m = 0; m < 8; ++m) d[(8 + m) * 256] = sb[m];
        #pragma unroll
        for (int m = 0; m < 8; ++m) sb[m] = sp[(24 + m) * 256];
        #pragma unroll
        for (int m = 0; m < 8; ++m) d[(16 + m) * 256] = sa[m];
        #pragma unroll
        for (int m = 0; m < 8; ++m) d[(24 + m) * 256] = sb[m];
    };

    auto compute = [&](int st, const int4 (&A)[8]) {
        #pragma unroll
        for (int kc = 0; kc < 4; ++kc) {
            const int4 Av = A[kc * 2 + 0], Ac = A[kc * 2 + 1];
            const int wbase = st * 128 + kc * 32 + quad * 8;
            const float4 Wa = *(const float4*)&wh2_lds[wbase];
            const float4 Wb = *(const float4*)&wh2_lds[wbase + 4];
            const float u0 = wh1i + Wa.x, u1 = wh1i + Wa.y;
            const float u2 = wh1i + Wa.z, u3 = wh1i + Wa.w;
            const float u4 = wh1i + Wb.x, u5 = wh1i + Wb.y;
            const float u6 = wh1i + Wb.z, u7 = wh1i + Wb.w;
            const float p0 = (Av.x > 0) ? __expf(fmaxf(u0, 0.2f * u0)) : 0.0f;
            const float p1 = (Av.y > 0) ? __expf(fmaxf(u1, 0.2f * u1)) : 0.0f;
            const float p2 = (Av.z > 0) ? __expf(fmaxf(u2, 0.2f * u2)) : 0.0f;
            const float p3 = (Av.w > 0) ? __expf(fmaxf(u3, 0.2f * u3)) : 0.0f;
            const float p4 = (Ac.x > 0) ? __expf(fmaxf(u4, 0.2f * u4)) : 0.0f;
            const float p5 = (Ac.y > 0) ? __expf(fmaxf(u5, 0.2f * u5)) : 0.0f;
            const float p6 = (Ac.z > 0) ? __expf(fmaxf(u6, 0.2f * u6)) : 0.0f;
            const float p7 = (Ac.w > 0) ? __expf(fmaxf(u7, 0.2f * u7)) : 0.0f;
            lsum += ((p0 + p1) + (p2 + p3)) + ((p4 + p5) + (p6 + p7));
            short8_t af;
            af[0] = (short)f2bf(p0); af[1] = (short)f2bf(p1);
            af[2] = (short)f2bf(p2); af[3] = (short)f2bf(p3);
            af[4] = (short)f2bf(p4); af[5] = (short)f2bf(p5);
            af[6] = (short)f2bf(p6); af[7] = (short)f2bf(p7);
            // B within current slab: 32-col chunk (st&3)*4 + kc
            const ushort_t* Bp = B_lds + ((st & 3) * 4 + kc) * 4096 + lane * 8;
            #pragma unroll
            for (int dt = 0; dt < 8; ++dt) {
                const short8_t Bf = *(const short8_t*)(Bp + dt * 512);
                acc[dt] = __builtin_amdgcn_mfma_f32_16x16x32_bf16(af, Bf, acc[dt], 0, 0, 0);
            }
        }
    };

    // ---- prologue: adj distance-2 + slab 0 ----
    adj_load(0, A0);
    adj_load(1, A1);
    stage(0);
    __syncthreads();

    // ---- fully unrolled: 6 slabs x 4 steps, adj rotation fully static ----
    #pragma unroll
    for (int sl = 0; sl < SLABS; ++sl) {
        if (sl > 0) {
            __syncthreads();    // all waves done reading previous slab
            stage(sl);
            __syncthreads();    // new slab visible
        }
        #pragma unroll
        for (int q = 0; q < 4; ++q) {
            const int st = sl * 4 + q;
            if (st + 2 < CSTEPS) {
                if (((st + 2) % 3) == 0)      adj_load(st + 2, A0);
                else if (((st + 2) % 3) == 1) adj_load(st + 2, A1);
                else                          adj_load(st + 2, A2);
            }
            if ((st % 3) == 0)      compute(st, A0);
            else if ((st % 3) == 1) compute(st, A1);
            else                    compute(st, A2);
        }
    }

    // ---- epilogue: one partial per column-quarter ----
    float v = lsum;
    v += __shfl_xor(v, 16);
    v += __shfl_xor(v, 32);
    if (quad == 0) plsum[(size_t)cy * NN + rowbase + l15] = v;
    #pragma unroll
    for (int dt = 0; dt < 8; ++dt)
        #pragma unroll
        for (int reg = 0; reg < 4; ++reg)
            pout[((size_t)cy * NN + rowbase + quad * 4 + reg) * DD + dt * 16 + l15]
                = acc[dt][reg];
}

// ---------------- Kernel 4: combine partials + normalize + expmap0 + proj ----
__global__ __launch_bounds__(128) void reduce_kernel(
    const float* __restrict__ pout, const float* __restrict__ plsum,
    float* __restrict__ out)
{
    const int i = blockIdx.x;
    const int t = threadIdx.x;
    float v = 0.0f;
    #pragma unroll
    for (int s = 0; s < CSPLIT; ++s) v += pout[((size_t)s * NN + i) * DD + t];
    float ls = 0.0f;
    #pragma unroll
    for (int s = 0; s < CSPLIT; ++s) ls += plsum[(size_t)s * NN + i];
    v /= ls;
    float ss = v * v;
    #pragma unroll
    for (int o = 1; o < 64; o <<= 1) ss += __shfl_xor(ss, o);
    __shared__ float r2[2];
    if ((t & 63) == 0) r2[t >> 6] = ss;
    __syncthreads();
    const float total = r2[0] + r2[1];
    const float nraw = sqrtf(total);
    const float nv   = fmaxf(nraw, EPSF);
    const float th   = tanhf(nv);
    const float ysc  = th / nv;
    const float nyr  = ysc * nraw;
    const float ny   = fmaxf(nyr, EPSF);
    const float psc  = (ny > MAXNORM) ? (MAXNORM / ny) : 1.0f;
    const float os   = ysc * psc;
    out[(size_t)i * DD + t] = v * os;
}

extern "C" void kernel_launch(void* const* d_in, const int* in_sizes, int n_in,
                              void* d_out, int out_size, void* d_ws, size_t ws_size,
                              hipStream_t stream) {
    const float* x   = (const float*)d_in[0];
    const int*   adj = (const int*)d_in[1];
    const float* a   = (const float*)d_in[2];
    float* out = (float*)d_out;

    // ---- workspace layout (~31 MB; ws is ~2.4 GB) ----
    char* ws = (char*)d_ws;
    ushort_t* xtb = (ushort_t*)ws;  ws += (size_t)NN * DD * sizeof(ushort_t);
    ushort_t* xtB = (ushort_t*)ws;  ws += (size_t)NN * DD * sizeof(ushort_t);
    float* wh1 = (float*)ws;        ws += NN * sizeof(float);
    float* wh2 = (float*)ws;        ws += NN * sizeof(float);
    float* plsum = (float*)ws;      ws += (size_t)CSPLIT * NN * sizeof(float);
    float* pout  = (float*)ws;

    prep_kernel<<<NN, 128, 0, stream>>>(x, a, xtb, wh1, wh2);
    swizzle_kernel<<<NN / 32, 256, 0, stream>>>(xtb, xtB);
    attn_kernel<<<dim3(NN / 64, CSPLIT), 256, 0, stream>>>(
        adj, xtB, wh1, wh2, pout, plsum);
    reduce_kernel<<<NN, 128, 0, stream>>>(pout, plsum, out);
}

// Round 7
// 1089.846 us; speedup vs baseline: 1.0992x; 1.0992x over previous
//
#include <hip/hip_runtime.h>
#include <math.h>

#define NN 12288
#define DD 128
#define EPSF 1e-7f
#define MAXNORM (1.0f - 1e-3f)
#define CSPLIT 4
#define CCOLS (NN / CSPLIT)      /* 3072 columns per block */
#define CSTEPS (CCOLS / 128)     /* 24 steps of 128 columns */
#define SLABS (CSTEPS / 4)       /* 6 LDS slabs of 512 columns */

typedef __attribute__((ext_vector_type(8))) short short8_t;
typedef __attribute__((ext_vector_type(4))) float float4_t;
typedef unsigned short ushort_t;

__device__ __forceinline__ unsigned short f2bf(float f) {
    unsigned int u = __builtin_bit_cast(unsigned int, f);
    unsigned int r = u + 0x7FFFu + ((u >> 16) & 1u);
    return (unsigned short)(r >> 16);
}

// ---------------- Kernel 1: per-row prep ----------------
__global__ __launch_bounds__(128) void prep_kernel(
    const float* __restrict__ x, const float* __restrict__ a,
    ushort_t* __restrict__ xtb,
    float* __restrict__ wh1, float* __restrict__ wh2)
{
    const int r = blockIdx.x;
    const int t = threadIdx.x;
    const float xv = x[r * DD + t];
    const float a1 = a[t];
    const float a2 = a[DD + t];
    float s0 = xv * xv, s1 = xv * a1, s2 = xv * a2;
    #pragma unroll
    for (int o = 32; o > 0; o >>= 1) {
        s0 += __shfl_xor(s0, o);
        s1 += __shfl_xor(s1, o);
        s2 += __shfl_xor(s2, o);
    }
    __shared__ float red[6];
    const int w = t >> 6;
    if ((t & 63) == 0) { red[w * 3 + 0] = s0; red[w * 3 + 1] = s1; red[w * 3 + 2] = s2; }
    __syncthreads();
    const float sumsq = red[0] + red[3];
    const float d1    = red[1] + red[4];
    const float d2    = red[2] + red[5];
    const float nraw  = sqrtf(sumsq);
    const float nrm   = fminf(fmaxf(nraw, EPSF), 1.0f - EPSF);
    const float scale = atanhf(nrm) / nrm;
    xtb[(size_t)r * DD + t] = f2bf(xv * scale);
    if (t == 0) {
        wh1[r] = scale * d1;
        wh2[r] = scale * d2;
    }
}

// ---------------- Kernel 2: build xtB in MFMA-B-fragment-linear layout ----
// chunk C (32 j), dt: 1 KB block; element (lane, e) = xt[C*32+(lane>>4)*8+e][dt*16+(lane&15)]
__global__ __launch_bounds__(256) void swizzle_kernel(
    const ushort_t* __restrict__ xtb, ushort_t* __restrict__ xtB)
{
    __shared__ ushort_t raw[32 * 136];
    const int C = blockIdx.x;
    const int t = threadIdx.x;
    #pragma unroll
    for (int p = 0; p < 2; ++p) {
        const int idx = p * 256 + t;
        const int j = idx >> 4, cell = idx & 15;
        const uint4 v = *(const uint4*)(xtb + (size_t)(C * 32 + j) * DD + cell * 8);
        *(uint4*)&raw[j * 136 + cell * 8] = v;
    }
    __syncthreads();
    #pragma unroll
    for (int p = 0; p < 2; ++p) {
        const int oc = p * 256 + t;       // 0..511 = dt*64 + lane
        const int dt = oc >> 6;
        const int l6 = oc & 63;
        const int l15 = l6 & 15, q = l6 >> 4;
        short8_t v;
        #pragma unroll
        for (int e = 0; e < 8; ++e)
            v[e] = (short)raw[(q * 8 + e) * 136 + dt * 16 + l15];
        *(short8_t*)(xtB + (size_t)C * 4096 + oc * 8) = v;
    }
}

// ---------------- Kernel 3: flash MFMA attention, slab-sequential B ----------
// Same structure as round 6 EXCEPT staging: the 128 KB slab restage now uses
// __builtin_amdgcn_global_load_lds (width=16, async DMA, zero staging VGPRs).
// Round 6 spilled (VGPR=256, 275 MB scratch round-trip) because the reg
// ping-pong stage held 64 live temporaries on top of the 96-reg adj rotation.
// xtB's fragment-linear layout is exactly the wave-uniform-base + lane*16
// destination pattern global_load_lds requires.
__global__ __launch_bounds__(256, 1) void attn_kernel(
    const int* __restrict__ adj,
    const ushort_t* __restrict__ xtB,
    const float* __restrict__ wh1, const float* __restrict__ wh2,
    float* __restrict__ pout, float* __restrict__ plsum)
{
    __shared__ __align__(16) ushort_t B_lds[512 * DD];   // 128 KB
    __shared__ __align__(16) float wh2_lds[CCOLS];       // 12 KB

    const int t = threadIdx.x;
    const int w = t >> 6, lane = t & 63;
    const int l15 = lane & 15, quad = lane >> 4;
    const int cy = blockIdx.y;
    const int jcol0 = cy * CCOLS;
    const int rowbase = blockIdx.x * 64 + w * 16;    // wave's 16 rows

    #pragma unroll
    for (int m = 0; m < CCOLS / 256; ++m)
        wh2_lds[m * 256 + t] = wh2[jcol0 + m * 256 + t];
    const float wh1i = wh1[rowbase + l15];

    const int* adj_lane = adj + (size_t)(rowbase + l15) * NN + jcol0 + quad * 8;
    // slab sl = 128 KB contiguous: Bsrc + sl*8192 uint4
    const uint4* Bsrc = (const uint4*)(xtB + (size_t)(jcol0 >> 5) * 4096);

    float4_t acc[8];
    #pragma unroll
    for (int dt = 0; dt < 8; ++dt) acc[dt] = (float4_t)0.0f;
    float lsum = 0.0f;

    int4 A0[8], A1[8], A2[8];     // adj rotating buffers (static indexing)

    auto adj_load = [&](int st, int4 (&A)[8]) {
        const int* bp = adj_lane + st * 128;
        #pragma unroll
        for (int kc = 0; kc < 4; ++kc) {
            A[kc * 2 + 0] = *(const int4*)(bp + kc * 32);
            A[kc * 2 + 1] = *(const int4*)(bp + kc * 32 + 4);
        }
    };

    // stage one 512-col slab (128 KB) via async global->LDS DMA:
    // per call, lane l deposits 16 B at (wave-uniform base) + l*16 from its
    // own global address -- exactly the linear order of xtB. No VGPR staging.
    auto stage = [&](int sl) {
        const uint4* gp = Bsrc + (size_t)sl * 8192 + (size_t)w * 64 + lane;
        char* lb = (char*)B_lds + (size_t)w * 64 * 16;
        #pragma unroll
        for (int m = 0; m < 32; ++m) {
            __builtin_amdgcn_global_load_lds(
                (const __attribute__((address_space(1))) unsigned int*)(gp + m * 256),
                (__attribute__((address_space(3))) unsigned int*)(lb + (size_t)m * 256 * 16),
                16, 0, 0);
        }
    };

    auto compute = [&](int st, const int4 (&A)[8]) {
        #pragma unroll
        for (int kc = 0; kc < 4; ++kc) {
            const int4 Av = A[kc * 2 + 0], Ac = A[kc * 2 + 1];
            const int wbase = st * 128 + kc * 32 + quad * 8;
            const float4 Wa = *(const float4*)&wh2_lds[wbase];
            const float4 Wb = *(const float4*)&wh2_lds[wbase + 4];
            const float u0 = wh1i + Wa.x, u1 = wh1i + Wa.y;
            const float u2 = wh1i + Wa.z, u3 = wh1i + Wa.w;
            const float u4 = wh1i + Wb.x, u5 = wh1i + Wb.y;
            const float u6 = wh1i + Wb.z, u7 = wh1i + Wb.w;
            const float p0 = (Av.x > 0) ? __expf(fmaxf(u0, 0.2f * u0)) : 0.0f;
            const float p1 = (Av.y > 0) ? __expf(fmaxf(u1, 0.2f * u1)) : 0.0f;
            const float p2 = (Av.z > 0) ? __expf(fmaxf(u2, 0.2f * u2)) : 0.0f;
            const float p3 = (Av.w > 0) ? __expf(fmaxf(u3, 0.2f * u3)) : 0.0f;
            const float p4 = (Ac.x > 0) ? __expf(fmaxf(u4, 0.2f * u4)) : 0.0f;
            const float p5 = (Ac.y > 0) ? __expf(fmaxf(u5, 0.2f * u5)) : 0.0f;
            const float p6 = (Ac.z > 0) ? __expf(fmaxf(u6, 0.2f * u6)) : 0.0f;
            const float p7 = (Ac.w > 0) ? __expf(fmaxf(u7, 0.2f * u7)) : 0.0f;
            lsum += ((p0 + p1) + (p2 + p3)) + ((p4 + p5) + (p6 + p7));
            short8_t af;
            af[0] = (short)f2bf(p0); af[1] = (short)f2bf(p1);
            af[2] = (short)f2bf(p2); af[3] = (short)f2bf(p3);
            af[4] = (short)f2bf(p4); af[5] = (short)f2bf(p5);
            af[6] = (short)f2bf(p6); af[7] = (short)f2bf(p7);
            // B within current slab: 32-col chunk (st&3)*4 + kc
            const ushort_t* Bp = B_lds + ((st & 3) * 4 + kc) * 4096 + lane * 8;
            #pragma unroll
            for (int dt = 0; dt < 8; ++dt) {
                const short8_t Bf = *(const short8_t*)(Bp + dt * 512);
                acc[dt] = __builtin_amdgcn_mfma_f32_16x16x32_bf16(af, Bf, acc[dt], 0, 0, 0);
            }
        }
    };

    // ---- prologue: adj distance-2 + slab 0 ----
    adj_load(0, A0);
    adj_load(1, A1);
    stage(0);
    __syncthreads();   // drains the DMA (vmcnt) + syncs waves

    // ---- fully unrolled: 6 slabs x 4 steps, adj rotation fully static ----
    #pragma unroll
    for (int sl = 0; sl < SLABS; ++sl) {
        if (sl > 0) {
            __syncthreads();    // all waves done reading previous slab
            stage(sl);
            __syncthreads();    // DMA drained -> new slab visible
        }
        #pragma unroll
        for (int q = 0; q < 4; ++q) {
            const int st = sl * 4 + q;
            if (st + 2 < CSTEPS) {
                if (((st + 2) % 3) == 0)      adj_load(st + 2, A0);
                else if (((st + 2) % 3) == 1) adj_load(st + 2, A1);
                else                          adj_load(st + 2, A2);
            }
            if ((st % 3) == 0)      compute(st, A0);
            else if ((st % 3) == 1) compute(st, A1);
            else                    compute(st, A2);
        }
    }

    // ---- epilogue: one partial per column-quarter ----
    float v = lsum;
    v += __shfl_xor(v, 16);
    v += __shfl_xor(v, 32);
    if (quad == 0) plsum[(size_t)cy * NN + rowbase + l15] = v;
    #pragma unroll
    for (int dt = 0; dt < 8; ++dt)
        #pragma unroll
        for (int reg = 0; reg < 4; ++reg)
            pout[((size_t)cy * NN + rowbase + quad * 4 + reg) * DD + dt * 16 + l15]
                = acc[dt][reg];
}

// ---------------- Kernel 4: combine partials + normalize + expmap0 + proj ----
__global__ __launch_bounds__(128) void reduce_kernel(
    const float* __restrict__ pout, const float* __restrict__ plsum,
    float* __restrict__ out)
{
    const int i = blockIdx.x;
    const int t = threadIdx.x;
    float v = 0.0f;
    #pragma unroll
    for (int s = 0; s < CSPLIT; ++s) v += pout[((size_t)s * NN + i) * DD + t];
    float ls = 0.0f;
    #pragma unroll
    for (int s = 0; s < CSPLIT; ++s) ls += plsum[(size_t)s * NN + i];
    v /= ls;
    float ss = v * v;
    #pragma unroll
    for (int o = 1; o < 64; o <<= 1) ss += __shfl_xor(ss, o);
    __shared__ float r2[2];
    if ((t & 63) == 0) r2[t >> 6] = ss;
    __syncthreads();
    const float total = r2[0] + r2[1];
    const float nraw = sqrtf(total);
    const float nv   = fmaxf(nraw, EPSF);
    const float th   = tanhf(nv);
    const float ysc  = th / nv;
    const float nyr  = ysc * nraw;
    const float ny   = fmaxf(nyr, EPSF);
    const float psc  = (ny > MAXNORM) ? (MAXNORM / ny) : 1.0f;
    const float os   = ysc * psc;
    out[(size_t)i * DD + t] = v * os;
}

extern "C" void kernel_launch(void* const* d_in, const int* in_sizes, int n_in,
                              void* d_out, int out_size, void* d_ws, size_t ws_size,
                              hipStream_t stream) {
    const float* x   = (const float*)d_in[0];
    const int*   adj = (const int*)d_in[1];
    const float* a   = (const float*)d_in[2];
    float* out = (float*)d_out;

    // ---- workspace layout (~31 MB; ws is ~2.4 GB) ----
    char* ws = (char*)d_ws;
    ushort_t* xtb = (ushort_t*)ws;  ws += (size_t)NN * DD * sizeof(ushort_t);
    ushort_t* xtB = (ushort_t*)ws;  ws += (size_t)NN * DD * sizeof(ushort_t);
    float* wh1 = (float*)ws;        ws += NN * sizeof(float);
    float* wh2 = (float*)ws;        ws += NN * sizeof(float);
    float* plsum = (float*)ws;      ws += (size_t)CSPLIT * NN * sizeof(float);
    float* pout  = (float*)ws;

    prep_kernel<<<NN, 128, 0, stream>>>(x, a, xtb, wh1, wh2);
    swizzle_kernel<<<NN / 32, 256, 0, stream>>>(xtb, xtB);
    attn_kernel<<<dim3(NN / 64, CSPLIT), 256, 0, stream>>>(
        adj, xtB, wh1, wh2, pout, plsum);
    reduce_kernel<<<NN, 128, 0, stream>>>(pout, plsum, out);
}

// Round 8
// 857.162 us; speedup vs baseline: 1.3976x; 1.2715x over previous
//
#include <hip/hip_runtime.h>
#include <math.h>

#define NN 12288
#define DD 128
#define EPSF 1e-7f
#define MAXNORM (1.0f - 1e-3f)
#define CSPLIT 4
#define CCOLS (NN / CSPLIT)      /* 3072 columns per block */
#define CSTEPS (CCOLS / 128)     /* 24 steps of 128 columns */
#define SLABS (CSTEPS / 4)       /* 6 LDS slabs of 512 columns */

typedef __attribute__((ext_vector_type(8))) short short8_t;
typedef __attribute__((ext_vector_type(4))) float float4_t;
typedef unsigned short ushort_t;

__device__ __forceinline__ unsigned short f2bf(float f) {
    unsigned int u = __builtin_bit_cast(unsigned int, f);
    unsigned int r = u + 0x7FFFu + ((u >> 16) & 1u);
    return (unsigned short)(r >> 16);
}

// ---------------- Kernel 1: per-row prep ----------------
__global__ __launch_bounds__(128) void prep_kernel(
    const float* __restrict__ x, const float* __restrict__ a,
    ushort_t* __restrict__ xtb,
    float* __restrict__ wh1, float* __restrict__ wh2)
{
    const int r = blockIdx.x;
    const int t = threadIdx.x;
    const float xv = x[r * DD + t];
    const float a1 = a[t];
    const float a2 = a[DD + t];
    float s0 = xv * xv, s1 = xv * a1, s2 = xv * a2;
    #pragma unroll
    for (int o = 32; o > 0; o >>= 1) {
        s0 += __shfl_xor(s0, o);
        s1 += __shfl_xor(s1, o);
        s2 += __shfl_xor(s2, o);
    }
    __shared__ float red[6];
    const int w = t >> 6;
    if ((t & 63) == 0) { red[w * 3 + 0] = s0; red[w * 3 + 1] = s1; red[w * 3 + 2] = s2; }
    __syncthreads();
    const float sumsq = red[0] + red[3];
    const float d1    = red[1] + red[4];
    const float d2    = red[2] + red[5];
    const float nraw  = sqrtf(sumsq);
    const float nrm   = fminf(fmaxf(nraw, EPSF), 1.0f - EPSF);
    const float scale = atanhf(nrm) / nrm;
    xtb[(size_t)r * DD + t] = f2bf(xv * scale);
    if (t == 0) {
        wh1[r] = scale * d1;
        wh2[r] = scale * d2;
    }
}

// ---------------- Kernel 2: build xtB in MFMA-B-fragment-linear layout ----
// chunk C (32 j), dt: 1 KB block; element (lane, e) = xt[C*32+(lane>>4)*8+e][dt*16+(lane&15)]
__global__ __launch_bounds__(256) void swizzle_kernel(
    const ushort_t* __restrict__ xtb, ushort_t* __restrict__ xtB)
{
    __shared__ ushort_t raw[32 * 136];
    const int C = blockIdx.x;
    const int t = threadIdx.x;
    #pragma unroll
    for (int p = 0; p < 2; ++p) {
        const int idx = p * 256 + t;
        const int j = idx >> 4, cell = idx & 15;
        const uint4 v = *(const uint4*)(xtb + (size_t)(C * 32 + j) * DD + cell * 8);
        *(uint4*)&raw[j * 136 + cell * 8] = v;
    }
    __syncthreads();
    #pragma unroll
    for (int p = 0; p < 2; ++p) {
        const int oc = p * 256 + t;       // 0..511 = dt*64 + lane
        const int dt = oc >> 6;
        const int l6 = oc & 63;
        const int l15 = l6 & 15, q = l6 >> 4;
        short8_t v;
        #pragma unroll
        for (int e = 0; e < 8; ++e)
            v[e] = (short)raw[(q * 8 + e) * 136 + dt * 16 + l15];
        *(short8_t*)(xtB + (size_t)C * 4096 + oc * 8) = v;
    }
}

// ---------------- Kernel 3: flash MFMA attention, slab-sequential B ----------
// Round-7 diff: kill the 275 MB scratch spill (VGPR was 256, WRITE 301 MB).
// (1) adj prefetch: distance-1 DOUBLE buffer Ra/Rb (64 VGPR) instead of the
//     distance-2 triple rotation (96 VGPR).
// (2) slab loop is '#pragma unroll 1' (runtime sl): no 24-copy code bloat,
//     no cross-slab load/address hoisting. Inner 4 steps stay unrolled, so
//     buffer alternation and the B-chunk index (q*4+kc) remain static.
// Staging stays global_load_lds (async DMA, zero staging VGPRs).
__global__ __launch_bounds__(256, 1) void attn_kernel(
    const int* __restrict__ adj,
    const ushort_t* __restrict__ xtB,
    const float* __restrict__ wh1, const float* __restrict__ wh2,
    float* __restrict__ pout, float* __restrict__ plsum)
{
    __shared__ __align__(16) ushort_t B_lds[512 * DD];   // 128 KB
    __shared__ __align__(16) float wh2_lds[CCOLS];       // 12 KB

    const int t = threadIdx.x;
    const int w = t >> 6, lane = t & 63;
    const int l15 = lane & 15, quad = lane >> 4;
    const int cy = blockIdx.y;
    const int jcol0 = cy * CCOLS;
    const int rowbase = blockIdx.x * 64 + w * 16;    // wave's 16 rows

    #pragma unroll
    for (int m = 0; m < CCOLS / 256; ++m)
        wh2_lds[m * 256 + t] = wh2[jcol0 + m * 256 + t];
    const float wh1i = wh1[rowbase + l15];

    const int* adj_lane = adj + (size_t)(rowbase + l15) * NN + jcol0 + quad * 8;
    // slab sl = 128 KB contiguous: Bsrc + sl*8192 uint4
    const uint4* Bsrc = (const uint4*)(xtB + (size_t)(jcol0 >> 5) * 4096);

    float4_t acc[8];
    #pragma unroll
    for (int dt = 0; dt < 8; ++dt) acc[dt] = (float4_t)0.0f;
    float lsum = 0.0f;

    int4 Ra[8], Rb[8];     // adj double buffer, distance-1 (static indexing)

    auto adj_load = [&](int st, int4 (&A)[8]) {
        const int* bp = adj_lane + st * 128;
        #pragma unroll
        for (int kc = 0; kc < 4; ++kc) {
            A[kc * 2 + 0] = *(const int4*)(bp + kc * 32);
            A[kc * 2 + 1] = *(const int4*)(bp + kc * 32 + 4);
        }
    };

    // stage one 512-col slab (128 KB) via async global->LDS DMA:
    // lane l deposits 16 B at (wave-uniform base) + l*16 from its own global
    // address -- exactly the linear order of xtB. No VGPR staging.
    auto stage = [&](int sl) {
        const uint4* gp = Bsrc + (size_t)sl * 8192 + (size_t)w * 64 + lane;
        char* lb = (char*)B_lds + (size_t)w * 64 * 16;
        #pragma unroll
        for (int m = 0; m < 32; ++m) {
            __builtin_amdgcn_global_load_lds(
                (const __attribute__((address_space(1))) unsigned int*)(gp + m * 256),
                (__attribute__((address_space(3))) unsigned int*)(lb + (size_t)m * 256 * 16),
                16, 0, 0);
        }
    };

    auto compute = [&](int st, int q, const int4 (&A)[8]) {
        #pragma unroll
        for (int kc = 0; kc < 4; ++kc) {
            const int4 Av = A[kc * 2 + 0], Ac = A[kc * 2 + 1];
            const int wbase = st * 128 + kc * 32 + quad * 8;
            const float4 Wa = *(const float4*)&wh2_lds[wbase];
            const float4 Wb = *(const float4*)&wh2_lds[wbase + 4];
            const float u0 = wh1i + Wa.x, u1 = wh1i + Wa.y;
            const float u2 = wh1i + Wa.z, u3 = wh1i + Wa.w;
            const float u4 = wh1i + Wb.x, u5 = wh1i + Wb.y;
            const float u6 = wh1i + Wb.z, u7 = wh1i + Wb.w;
            const float p0 = (Av.x > 0) ? __expf(fmaxf(u0, 0.2f * u0)) : 0.0f;
            const float p1 = (Av.y > 0) ? __expf(fmaxf(u1, 0.2f * u1)) : 0.0f;
            const float p2 = (Av.z > 0) ? __expf(fmaxf(u2, 0.2f * u2)) : 0.0f;
            const float p3 = (Av.w > 0) ? __expf(fmaxf(u3, 0.2f * u3)) : 0.0f;
            const float p4 = (Ac.x > 0) ? __expf(fmaxf(u4, 0.2f * u4)) : 0.0f;
            const float p5 = (Ac.y > 0) ? __expf(fmaxf(u5, 0.2f * u5)) : 0.0f;
            const float p6 = (Ac.z > 0) ? __expf(fmaxf(u6, 0.2f * u6)) : 0.0f;
            const float p7 = (Ac.w > 0) ? __expf(fmaxf(u7, 0.2f * u7)) : 0.0f;
            lsum += ((p0 + p1) + (p2 + p3)) + ((p4 + p5) + (p6 + p7));
            short8_t af;
            af[0] = (short)f2bf(p0); af[1] = (short)f2bf(p1);
            af[2] = (short)f2bf(p2); af[3] = (short)f2bf(p3);
            af[4] = (short)f2bf(p4); af[5] = (short)f2bf(p5);
            af[6] = (short)f2bf(p6); af[7] = (short)f2bf(p7);
            // B within current slab: 32-col chunk q*4 + kc (static)
            const ushort_t* Bp = B_lds + (q * 4 + kc) * 4096 + lane * 8;
            #pragma unroll
            for (int dt = 0; dt < 8; ++dt) {
                const short8_t Bf = *(const short8_t*)(Bp + dt * 512);
                acc[dt] = __builtin_amdgcn_mfma_f32_16x16x32_bf16(af, Bf, acc[dt], 0, 0, 0);
            }
        }
    };

    // ---- prologue: adj steps 0,1 in flight ----
    adj_load(0, Ra);
    adj_load(1, Rb);

    // ---- slab loop: runtime sl (NOT unrolled), 4 static steps inside ----
    #pragma unroll 1
    for (int sl = 0; sl < SLABS; ++sl) {
        const int st0 = sl * 4;
        __syncthreads();            // all waves done reading previous slab
        stage(sl);                  // async DMA this slab's B
        __syncthreads();            // DMA drained -> slab visible
        // q=0
        compute(st0 + 0, 0, Ra);
        if (st0 + 2 < CSTEPS) adj_load(st0 + 2, Ra);
        // q=1
        compute(st0 + 1, 1, Rb);
        if (st0 + 3 < CSTEPS) adj_load(st0 + 3, Rb);
        // q=2
        compute(st0 + 2, 2, Ra);
        if (st0 + 4 < CSTEPS) adj_load(st0 + 4, Ra);
        // q=3
        compute(st0 + 3, 3, Rb);
        if (st0 + 5 < CSTEPS) adj_load(st0 + 5, Rb);
    }

    // ---- epilogue: one partial per column-quarter ----
    float v = lsum;
    v += __shfl_xor(v, 16);
    v += __shfl_xor(v, 32);
    if (quad == 0) plsum[(size_t)cy * NN + rowbase + l15] = v;
    #pragma unroll
    for (int dt = 0; dt < 8; ++dt)
        #pragma unroll
        for (int reg = 0; reg < 4; ++reg)
            pout[((size_t)cy * NN + rowbase + quad * 4 + reg) * DD + dt * 16 + l15]
                = acc[dt][reg];
}

// ---------------- Kernel 4: combine partials + normalize + expmap0 + proj ----
__global__ __launch_bounds__(128) void reduce_kernel(
    const float* __restrict__ pout, const float* __restrict__ plsum,
    float* __restrict__ out)
{
    const int i = blockIdx.x;
    const int t = threadIdx.x;
    float v = 0.0f;
    #pragma unroll
    for (int s = 0; s < CSPLIT; ++s) v += pout[((size_t)s * NN + i) * DD + t];
    float ls = 0.0f;
    #pragma unroll
    for (int s = 0; s < CSPLIT; ++s) ls += plsum[(size_t)s * NN + i];
    v /= ls;
    float ss = v * v;
    #pragma unroll
    for (int o = 1; o < 64; o <<= 1) ss += __shfl_xor(ss, o);
    __shared__ float r2[2];
    if ((t & 63) == 0) r2[t >> 6] = ss;
    __syncthreads();
    const float total = r2[0] + r2[1];
    const float nraw = sqrtf(total);
    const float nv   = fmaxf(nraw, EPSF);
    const float th   = tanhf(nv);
    const float ysc  = th / nv;
    const float nyr  = ysc * nraw;
    const float ny   = fmaxf(nyr, EPSF);
    const float psc  = (ny > MAXNORM) ? (MAXNORM / ny) : 1.0f;
    const float os   = ysc * psc;
    out[(size_t)i * DD + t] = v * os;
}

extern "C" void kernel_launch(void* const* d_in, const int* in_sizes, int n_in,
                              void* d_out, int out_size, void* d_ws, size_t ws_size,
                              hipStream_t stream) {
    const float* x   = (const float*)d_in[0];
    const int*   adj = (const int*)d_in[1];
    const float* a   = (const float*)d_in[2];
    float* out = (float*)d_out;

    // ---- workspace layout (~31 MB; ws is ~2.4 GB) ----
    char* ws = (char*)d_ws;
    ushort_t* xtb = (ushort_t*)ws;  ws += (size_t)NN * DD * sizeof(ushort_t);
    ushort_t* xtB = (ushort_t*)ws;  ws += (size_t)NN * DD * sizeof(ushort_t);
    float* wh1 = (float*)ws;        ws += NN * sizeof(float);
    float* wh2 = (float*)ws;        ws += NN * sizeof(float);
    float* plsum = (float*)ws;      ws += (size_t)CSPLIT * NN * sizeof(float);
    float* pout  = (float*)ws;

    prep_kernel<<<NN, 128, 0, stream>>>(x, a, xtb, wh1, wh2);
    swizzle_kernel<<<NN / 32, 256, 0, stream>>>(xtb, xtB);
    attn_kernel<<<dim3(NN / 64, CSPLIT), 256, 0, stream>>>(
        adj, xtB, wh1, wh2, pout, plsum);
    reduce_kernel<<<NN, 128, 0, stream>>>(pout, plsum, out);
}

// Round 10
// 830.610 us; speedup vs baseline: 1.4423x; 1.0320x over previous
//
#include <hip/hip_runtime.h>
#include <math.h>

#define NN 12288
#define DD 128
#define EPSF 1e-7f
#define MAXNORM (1.0f - 1e-3f)
#define CSPLIT 8
#define CCOLS (NN / CSPLIT)      /* 1536 columns per block */
#define CSTEPS (CCOLS / 128)     /* 12 steps of 128 columns */
#define SLABS (CSTEPS / 2)       /* 6 LDS slabs of 256 columns (64 KB) */

typedef __attribute__((ext_vector_type(8))) short short8_t;
typedef __attribute__((ext_vector_type(4))) float float4_t;
typedef unsigned short ushort_t;

__device__ __forceinline__ unsigned short f2bf(float f) {
    unsigned int u = __builtin_bit_cast(unsigned int, f);
    unsigned int r = u + 0x7FFFu + ((u >> 16) & 1u);
    return (unsigned short)(r >> 16);
}

// ---------------- Kernel 1: per-row prep ----------------
__global__ __launch_bounds__(128) void prep_kernel(
    const float* __restrict__ x, const float* __restrict__ a,
    ushort_t* __restrict__ xtb,
    float* __restrict__ wh1, float* __restrict__ wh2)
{
    const int r = blockIdx.x;
    const int t = threadIdx.x;
    const float xv = x[r * DD + t];
    const float a1 = a[t];
    const float a2 = a[DD + t];
    float s0 = xv * xv, s1 = xv * a1, s2 = xv * a2;
    #pragma unroll
    for (int o = 32; o > 0; o >>= 1) {
        s0 += __shfl_xor(s0, o);
        s1 += __shfl_xor(s1, o);
        s2 += __shfl_xor(s2, o);
    }
    __shared__ float red[6];
    const int w = t >> 6;
    if ((t & 63) == 0) { red[w * 3 + 0] = s0; red[w * 3 + 1] = s1; red[w * 3 + 2] = s2; }
    __syncthreads();
    const float sumsq = red[0] + red[3];
    const float d1    = red[1] + red[4];
    const float d2    = red[2] + red[5];
    const float nraw  = sqrtf(sumsq);
    const float nrm   = fminf(fmaxf(nraw, EPSF), 1.0f - EPSF);
    const float scale = atanhf(nrm) / nrm;
    xtb[(size_t)r * DD + t] = f2bf(xv * scale);
    if (t == 0) {
        wh1[r] = scale * d1;
        wh2[r] = scale * d2;
    }
}

// ---------------- Kernel 2: build xtB in MFMA-B-fragment-linear layout ----
// chunk C (32 j), dt: 1 KB block; element (lane, e) = xt[C*32+(lane>>4)*8+e][dt*16+(lane&15)]
__global__ __launch_bounds__(256) void swizzle_kernel(
    const ushort_t* __restrict__ xtb, ushort_t* __restrict__ xtB)
{
    __shared__ ushort_t raw[32 * 136];
    const int C = blockIdx.x;
    const int t = threadIdx.x;
    #pragma unroll
    for (int p = 0; p < 2; ++p) {
        const int idx = p * 256 + t;
        const int j = idx >> 4, cell = idx & 15;
        const uint4 v = *(const uint4*)(xtb + (size_t)(C * 32 + j) * DD + cell * 8);
        *(uint4*)&raw[j * 136 + cell * 8] = v;
    }
    __syncthreads();
    #pragma unroll
    for (int p = 0; p < 2; ++p) {
        const int oc = p * 256 + t;       // 0..511 = dt*64 + lane
        const int dt = oc >> 6;
        const int l6 = oc & 63;
        const int l15 = l6 & 15, q = l6 >> 4;
        short8_t v;
        #pragma unroll
        for (int e = 0; e < 8; ++e)
            v[e] = (short)raw[(q * 8 + e) * 136 + dt * 16 + l15];
        *(short8_t*)(xtB + (size_t)C * 4096 + oc * 8) = v;
    }
}

// ---------------- Kernel 3: flash MFMA attention, 2 blocks/CU ----------------
// vs r8 (1 block/CU, ~240 us, 2.5x the 96 us adj-stream floor -- LDS/issue
// latency fully exposed at 1 wave/SIMD):
// (1) OCCUPANCY 2 blocks/CU: B slab 256 cols (64 KB) + wh2 6 KB (CSPLIT=8)
//     = 70 KB LDS; __launch_bounds__(256,2) caps VGPR at 128.
// (2) VGPR diet to fit 128: single 32-reg adj load buffer R + per-step u32
//     BITMASK (32 cols/lane/step = 1 bit each). Loads(st+1) fly during
//     compute(st); then wait+compress R->mask, issue loads(st+2).
// (3) grid 1536 blocks = exactly 3.0 rounds of 512 co-resident blocks.
__global__ __launch_bounds__(256, 2) void attn_kernel(
    const int* __restrict__ adj,
    const ushort_t* __restrict__ xtB,
    const float* __restrict__ wh1, const float* __restrict__ wh2,
    float* __restrict__ pout, float* __restrict__ plsum)
{
    __shared__ __align__(16) ushort_t B_lds[256 * DD];   // 64 KB
    __shared__ __align__(16) float wh2_lds[CCOLS];       //  6 KB

    const int t = threadIdx.x;
    const int w = t >> 6, lane = t & 63;
    const int l15 = lane & 15, quad = lane >> 4;
    const int cy = blockIdx.y;
    const int jcol0 = cy * CCOLS;
    const int rowbase = blockIdx.x * 64 + w * 16;    // wave's 16 rows

    #pragma unroll
    for (int m = 0; m < CCOLS / 256; ++m)
        wh2_lds[m * 256 + t] = wh2[jcol0 + m * 256 + t];
    const float wh1i = wh1[rowbase + l15];

    const int* adj_lane = adj + (size_t)(rowbase + l15) * NN + jcol0 + quad * 8;
    // slab sl = 64 KB contiguous: Bsrc + sl*4096 uint4
    const uint4* Bsrc = (const uint4*)(xtB + (size_t)(jcol0 >> 5) * 4096);

    float4_t acc[8];
    #pragma unroll
    for (int dt = 0; dt < 8; ++dt) acc[dt] = (float4_t)0.0f;
    float lsum = 0.0f;

    int4 R[8];             // single adj load buffer (static indexing)
    unsigned mCur;         // current step's 32-col bitmask (bit kc*8+e)

    auto adj_load = [&](int st) {
        const int* bp = adj_lane + st * 128;
        #pragma unroll
        for (int kc = 0; kc < 4; ++kc) {
            R[kc * 2 + 0] = *(const int4*)(bp + kc * 32);
            R[kc * 2 + 1] = *(const int4*)(bp + kc * 32 + 4);
        }
    };

    auto compress = [&]() -> unsigned {
        unsigned m = 0;
        #pragma unroll
        for (int kc = 0; kc < 4; ++kc) {
            const int4 a0 = R[kc * 2 + 0], a1 = R[kc * 2 + 1];
            m |= (a0.x > 0 ? 1u : 0u) << (kc * 8 + 0);
            m |= (a0.y > 0 ? 1u : 0u) << (kc * 8 + 1);
            m |= (a0.z > 0 ? 1u : 0u) << (kc * 8 + 2);
            m |= (a0.w > 0 ? 1u : 0u) << (kc * 8 + 3);
            m |= (a1.x > 0 ? 1u : 0u) << (kc * 8 + 4);
            m |= (a1.y > 0 ? 1u : 0u) << (kc * 8 + 5);
            m |= (a1.z > 0 ? 1u : 0u) << (kc * 8 + 6);
            m |= (a1.w > 0 ? 1u : 0u) << (kc * 8 + 7);
        }
        return m;
    };

    // stage one 256-col slab (64 KB) via async global->LDS DMA (no VGPRs)
    auto stage = [&](int sl) {
        const uint4* gp = Bsrc + (size_t)sl * 4096 + (size_t)w * 64 + lane;
        char* lb = (char*)B_lds + (size_t)w * 64 * 16;
        #pragma unroll
        for (int m = 0; m < 16; ++m) {
            __builtin_amdgcn_global_load_lds(
                (const __attribute__((address_space(1))) unsigned int*)(gp + m * 256),
                (__attribute__((address_space(3))) unsigned int*)(lb + (size_t)m * 256 * 16),
                16, 0, 0);
        }
    };

    auto compute = [&](int st, int par, unsigned mask) {
        #pragma unroll
        for (int kc = 0; kc < 4; ++kc) {
            const unsigned wq = (mask >> (kc * 8)) & 0xFFu;
            const int wbase = st * 128 + kc * 32 + quad * 8;
            const float4 Wa = *(const float4*)&wh2_lds[wbase];
            const float4 Wb = *(const float4*)&wh2_lds[wbase + 4];
            const float u0 = wh1i + Wa.x, u1 = wh1i + Wa.y;
            const float u2 = wh1i + Wa.z, u3 = wh1i + Wa.w;
            const float u4 = wh1i + Wb.x, u5 = wh1i + Wb.y;
            const float u6 = wh1i + Wb.z, u7 = wh1i + Wb.w;
            const float p0 = (wq & 1u)   ? __expf(fmaxf(u0, 0.2f * u0)) : 0.0f;
            const float p1 = (wq & 2u)   ? __expf(fmaxf(u1, 0.2f * u1)) : 0.0f;
            const float p2 = (wq & 4u)   ? __expf(fmaxf(u2, 0.2f * u2)) : 0.0f;
            const float p3 = (wq & 8u)   ? __expf(fmaxf(u3, 0.2f * u3)) : 0.0f;
            const float p4 = (wq & 16u)  ? __expf(fmaxf(u4, 0.2f * u4)) : 0.0f;
            const float p5 = (wq & 32u)  ? __expf(fmaxf(u5, 0.2f * u5)) : 0.0f;
            const float p6 = (wq & 64u)  ? __expf(fmaxf(u6, 0.2f * u6)) : 0.0f;
            const float p7 = (wq & 128u) ? __expf(fmaxf(u7, 0.2f * u7)) : 0.0f;
            lsum += ((p0 + p1) + (p2 + p3)) + ((p4 + p5) + (p6 + p7));
            short8_t af;
            af[0] = (short)f2bf(p0); af[1] = (short)f2bf(p1);
            af[2] = (short)f2bf(p2); af[3] = (short)f2bf(p3);
            af[4] = (short)f2bf(p4); af[5] = (short)f2bf(p5);
            af[6] = (short)f2bf(p6); af[7] = (short)f2bf(p7);
            // B within current slab: 32-col chunk par*4 + kc (static)
            const ushort_t* Bp = B_lds + (par * 4 + kc) * 4096 + lane * 8;
            #pragma unroll
            for (int dt = 0; dt < 8; ++dt) {
                const short8_t Bf = *(const short8_t*)(Bp + dt * 512);
                acc[dt] = __builtin_amdgcn_mfma_f32_16x16x32_bf16(af, Bf, acc[dt], 0, 0, 0);
            }
        }
    };

    // ---- prologue: mask(0) ready, loads(1) in flight ----
    adj_load(0);
    mCur = compress();
    adj_load(1);

    // ---- slab loop: runtime sl, 2 parity-static steps inside ----
    #pragma unroll 1
    for (int sl = 0; sl < SLABS; ++sl) {
        const int st0 = sl * 2;
        __syncthreads();            // all waves done reading previous slab
        stage(sl);                  // async DMA this slab's B
        __syncthreads();            // DMA drained -> slab visible
        // step A (parity 0): consume mask(st0); R holds data(st0+1)
        compute(st0 + 0, 0, mCur);
        mCur = compress();                        // waits loads(st0+1)
        if (st0 + 2 < CSTEPS) adj_load(st0 + 2);
        // step B (parity 1): consume mask(st0+1); R holds data(st0+2)
        compute(st0 + 1, 1, mCur);
        if (st0 + 2 < CSTEPS) {
            mCur = compress();                    // waits loads(st0+2)
            if (st0 + 3 < CSTEPS) adj_load(st0 + 3);
        }
    }

    // ---- epilogue: one partial per column-slice ----
    float v = lsum;
    v += __shfl_xor(v, 16);
    v += __shfl_xor(v, 32);
    if (quad == 0) plsum[(size_t)cy * NN + rowbase + l15] = v;
    #pragma unroll
    for (int dt = 0; dt < 8; ++dt)
        #pragma unroll
        for (int reg = 0; reg < 4; ++reg)
            pout[((size_t)cy * NN + rowbase + quad * 4 + reg) * DD + dt * 16 + l15]
                = acc[dt][reg];
}

// ---------------- Kernel 4: combine partials + normalize + expmap0 + proj ----
__global__ __launch_bounds__(128) void reduce_kernel(
    const float* __restrict__ pout, const float* __restrict__ plsum,
    float* __restrict__ out)
{
    const int i = blockIdx.x;
    const int t = threadIdx.x;
    float v = 0.0f;
    #pragma unroll
    for (int s = 0; s < CSPLIT; ++s) v += pout[((size_t)s * NN + i) * DD + t];
    float ls = 0.0f;
    #pragma unroll
    for (int s = 0; s < CSPLIT; ++s) ls += plsum[(size_t)s * NN + i];
    v /= ls;
    float ss = v * v;
    #pragma unroll
    for (int o = 1; o < 64; o <<= 1) ss += __shfl_xor(ss, o);
    __shared__ float r2[2];
    if ((t & 63) == 0) r2[t >> 6] = ss;
    __syncthreads();
    const float total = r2[0] + r2[1];
    const float nraw = sqrtf(total);
    const float nv   = fmaxf(nraw, EPSF);
    const float th   = tanhf(nv);
    const float ysc  = th / nv;
    const float nyr  = ysc * nraw;
    const float ny   = fmaxf(nyr, EPSF);
    const float psc  = (ny > MAXNORM) ? (MAXNORM / ny) : 1.0f;
    const float os   = ysc * psc;
    out[(size_t)i * DD + t] = v * os;
}

extern "C" void kernel_launch(void* const* d_in, const int* in_sizes, int n_in,
                              void* d_out, int out_size, void* d_ws, size_t ws_size,
                              hipStream_t stream) {
    const float* x   = (const float*)d_in[0];
    const int*   adj = (const int*)d_in[1];
    const float* a   = (const float*)d_in[2];
    float* out = (float*)d_out;

    // ---- workspace layout (~57 MB; ws is ~2.4 GB) ----
    char* ws = (char*)d_ws;
    ushort_t* xtb = (ushort_t*)ws;  ws += (size_t)NN * DD * sizeof(ushort_t);
    ushort_t* xtB = (ushort_t*)ws;  ws += (size_t)NN * DD * sizeof(ushort_t);
    float* wh1 = (float*)ws;        ws += NN * sizeof(float);
    float* wh2 = (float*)ws;        ws += NN * sizeof(float);
    float* plsum = (float*)ws;      ws += (size_t)CSPLIT * NN * sizeof(float);
    float* pout  = (float*)ws;

    prep_kernel<<<NN, 128, 0, stream>>>(x, a, xtb, wh1, wh2);
    swizzle_kernel<<<NN / 32, 256, 0, stream>>>(xtb, xtB);
    attn_kernel<<<dim3(NN / 64, CSPLIT), 256, 0, stream>>>(
        adj, xtB, wh1, wh2, pout, plsum);
    reduce_kernel<<<NN, 128, 0, stream>>>(pout, plsum, out);
}